// Round 13
// baseline (254.128 us; speedup 1.0000x reference)
//
#include <hip/hip_runtime.h>

#define E_EDGES 160000
#define N_NODES 10000

// 24^(-0.5)
#define TEMP 0.20412414523193154f

typedef __fp16 half2_t __attribute__((ext_vector_type(2)));
typedef __fp16 half8_t __attribute__((ext_vector_type(8)));
typedef float f32x4 __attribute__((ext_vector_type(4)));

__device__ __forceinline__ float fdot2(half2_t a, half2_t b, float c) {
#if __has_builtin(__builtin_amdgcn_fdot2)
    return __builtin_amdgcn_fdot2(a, b, c, false);
#else
    return fmaf((float)a.x, (float)b.x, fmaf((float)a.y, (float)b.y, c));
#endif
}
__device__ __forceinline__ half2_t pk(float a, float b) {
    return __builtin_amdgcn_cvt_pkrtz(a, b);
}

// W2 [768][64] f32 -> f16 in FRAGMENT order:
// u32 index u: tp=u&3, lane=(u>>2)&63, piece=(u>>8)&3, c=u>>10
// em=lane&15, quad=lane>>4; row=32c + (piece>>1)*16 + em; col=(piece&1)*32 + quad*8 + 2*tp
__global__ __launch_bounds__(256)
void w2cvt_kernel(const float* __restrict__ W2, unsigned* __restrict__ w2p)
{
    int u = blockIdx.x * blockDim.x + threadIdx.x;   // u < 24576
    int tp    = u & 3;
    int lane  = (u >> 2) & 63;
    int piece = (u >> 8) & 3;
    int c     = u >> 10;
    int em = lane & 15, quad = lane >> 4;
    int row = 32*c + ((piece >> 1) << 4) + em;
    int col = ((piece & 1) << 5) + quad*8 + 2*tp;
    union { half2_t h; unsigned v; } o;
    o.h.x = (__fp16)W2[row*64 + col];
    o.h.y = (__fp16)W2[row*64 + col + 1];
    w2p[u] = o.v;
}

// ---- fused per-edge kernel (R9 numerics), W2/W1/b2 staged in LDS ----
// Block = 1024 threads (16 waves), 16 edges/wave; LDS 107 KB -> 1 block/CU.
// launch_bounds min-residency arg MUST be 1: R12's (1024,4) capped VGPR at 64 -> spill.
__global__ __launch_bounds__(1024, 1)
void fused_kernel(const int* __restrict__ src,
                  const float* __restrict__ basis, const float* __restrict__ efeat,
                  const float* __restrict__ f,
                  const float* __restrict__ W1, const float* __restrict__ b1,
                  const uint4* __restrict__ w2p, const float* __restrict__ b2,
                  float* __restrict__ v_out, float* __restrict__ sc_out)
{
    __shared__ __fp16 w2s[24*4*64*8];   // 96 KB, [c][piece][lane][8]
    __shared__ float  w1s[64*32];       // 8 KB
    __shared__ float  b2s[768];         // 3 KB

    const int tid  = threadIdx.x;
    const int lane = tid & 63;
    const int wid  = tid >> 6;
    const int em   = lane & 15;
    const int quad = lane >> 4;
    const int e = (blockIdx.x * 16 + wid) * 16 + em;

    // ---- stage weights (contiguous copies) ----
    {
        uint4* d4 = (uint4*)w2s;
        #pragma unroll
        for (int i = 0; i < 6; ++i) d4[i*1024 + tid] = w2p[i*1024 + tid];
        w1s[tid] = W1[tid];
        w1s[1024 + tid] = W1[1024 + tid];
        if (tid < 768) b2s[tid] = b2[tid];
    }
    __syncthreads();

    // ---- Phase A: h = relu(x @ W1^T + b1), fp32 (W1 via LDS broadcast) ----
    half8_t h_lo, h_hi;
    {
        float x[32];
        const float4* xv = (const float4*)(efeat + (size_t)e * 32);
        #pragma unroll
        for (int i = 0; i < 8; ++i) {
            float4 t = xv[i];
            x[4*i+0] = t.x; x[4*i+1] = t.y; x[4*i+2] = t.z; x[4*i+3] = t.w;
        }
        union { __fp16 h[8]; half8_t v; } lo, hi;
        #pragma unroll
        for (int t = 0; t < 8; ++t) {
            const int j0 = quad*8 + t;
            const int j1 = 32 + quad*8 + t;
            float a0 = b1[j0], a1 = b1[j1];
            const float* __restrict__ w0 = w1s + j0*32;
            const float* __restrict__ w1 = w1s + j1*32;
            #pragma unroll
            for (int i = 0; i < 32; ++i) {
                a0 = fmaf(w0[i], x[i], a0);
                a1 = fmaf(w1[i], x[i], a1);
            }
            lo.h[t] = (__fp16)fmaxf(a0, 0.0f);
            hi.h[t] = (__fp16)fmaxf(a1, 0.0f);
        }
        h_lo = lo.v; h_hi = hi.v;
    }

    // ---- Phase B: tmp2 quarter (mp = quad*4..+4), pairs (m', m'+16) ----
    half2_t t2[4][3];
    {
        float bas[18];
        const float2* bv = (const float2*)(basis + (size_t)e * 18);
        #pragma unroll
        for (int i = 0; i < 9; ++i) { float2 t = bv[i]; bas[2*i] = t.x; bas[2*i+1] = t.y; }
        const float* fp = f + (size_t)src[e] * 48 + quad*6;
        float fl[6], fh[6];
        #pragma unroll
        for (int i = 0; i < 3; ++i) {
            float2 a = *(const float2*)(fp + 2*i);      fl[2*i] = a.x; fl[2*i+1] = a.y;
            float2 b = *(const float2*)(fp + 24 + 2*i); fh[2*i] = b.x; fh[2*i+1] = b.y;
        }
        #pragma unroll
        for (int jj = 0; jj < 4; ++jj) {
            const int mr = (jj >> 1) * 3;
            const int rb = (jj & 1) * 3;
            #pragma unroll
            for (int d = 0; d < 3; ++d) {
                float lo = fmaf(fl[mr+0], bas[rb+d],
                           fmaf(fl[mr+1], bas[6+rb+d], fl[mr+2] * bas[12+rb+d]));
                float hi = fmaf(fh[mr+0], bas[rb+d],
                           fmaf(fh[mr+1], bas[6+rb+d], fh[mr+2] * bas[12+rb+d]));
                t2[jj][d] = pk(lo, hi);
            }
        }
    }

    // ---- Phase C: 24 conv rows; W2 fragments from LDS ----
    float kreg[8][3], vreg[8][3], sreg[4];
    #pragma unroll
    for (int c = 0; c < 24; ++c) {
        const __fp16* base = w2s + ((c*4)*64 + lane)*8;
        half8_t wa0 = *(const half8_t*)(base);
        half8_t wa1 = *(const half8_t*)(base + 64*8);
        half8_t wb0 = *(const half8_t*)(base + 2*64*8);
        half8_t wb1 = *(const half8_t*)(base + 3*64*8);
        float4 bb0 = *(const float4*)(b2s + 32*c + quad*4);
        float4 bb1 = *(const float4*)(b2s + 32*c + 16 + quad*4);

        f32x4 acc0 = {bb0.x, bb0.y, bb0.z, bb0.w};
        acc0 = __builtin_amdgcn_mfma_f32_16x16x32_f16(wa0, h_lo, acc0, 0, 0, 0);
        acc0 = __builtin_amdgcn_mfma_f32_16x16x32_f16(wa1, h_hi, acc0, 0, 0, 0);
        f32x4 acc1 = {bb1.x, bb1.y, bb1.z, bb1.w};
        acc1 = __builtin_amdgcn_mfma_f32_16x16x32_f16(wb0, h_lo, acc1, 0, 0, 0);
        acc1 = __builtin_amdgcn_mfma_f32_16x16x32_f16(wb1, h_hi, acc1, 0, 0, 0);

        float p0 = 0.f, p1 = 0.f, p2 = 0.f;
        #pragma unroll
        for (int r = 0; r < 4; ++r) {
            half2_t rp = pk(acc0[r], acc1[r]);
            p0 = fdot2(rp, t2[r][0], p0);
            p1 = fdot2(rp, t2[r][1], p1);
            p2 = fdot2(rp, t2[r][2], p2);
        }
        p0 += __shfl_xor(p0, 16); p0 += __shfl_xor(p0, 32);
        p1 += __shfl_xor(p1, 16); p1 += __shfl_xor(p1, 32);
        p2 += __shfl_xor(p2, 16); p2 += __shfl_xor(p2, 32);

        if (c < 8)       { kreg[c][0]=p0; kreg[c][1]=p1; kreg[c][2]=p2; }
        else if (c < 16) {
            float s_ = p0*kreg[c-8][0] + p1*kreg[c-8][1] + p2*kreg[c-8][2];
            if (((c)&1)==0) sreg[(c-8)>>1] = s_; else sreg[(c-8)>>1] += s_;
        }
        else             { vreg[c-16][0]=p0; vreg[c-16][1]=p1; vreg[c-16][2]=p2; }
    }

    // ---- Epilogue ----
    #pragma unroll
    for (int hh = 0; hh < 4; ++hh) {
        float s = sreg[hh] * TEMP;
        sreg[hh] = (s > 0.0f) ? s : 0.2f * s;
    }
    float* vb = v_out + (size_t)e * 24;
    if (quad == 3) {
        *(float4*)(sc_out + (size_t)e*4) = make_float4(sreg[0], sreg[1], sreg[2], sreg[3]);
    } else if (quad == 0) {
        *(float4*)(vb+0) = make_float4(vreg[0][0], vreg[0][1], vreg[0][2], vreg[1][0]);
        *(float4*)(vb+4) = make_float4(vreg[1][1], vreg[1][2], vreg[2][0], vreg[2][1]);
    } else if (quad == 1) {
        *(float4*)(vb+8)  = make_float4(vreg[2][2], vreg[3][0], vreg[3][1], vreg[3][2]);
        *(float4*)(vb+12) = make_float4(vreg[4][0], vreg[4][1], vreg[4][2], vreg[5][0]);
    } else {
        *(float4*)(vb+16) = make_float4(vreg[5][1], vreg[5][2], vreg[6][0], vreg[6][1]);
        *(float4*)(vb+20) = make_float4(vreg[6][2], vreg[7][0], vreg[7][1], vreg[7][2]);
    }
}

// ---- CSR build: histogram -> exclusive scan -> index scatter ----
__global__ __launch_bounds__(256)
void hist_kernel(const int* __restrict__ dst, int* __restrict__ cnt)
{
    int e = blockIdx.x * blockDim.x + threadIdx.x;
    if (e < E_EDGES) atomicAdd(&cnt[dst[e]], 1);
}

__global__ __launch_bounds__(256)
void scan_kernel(const int* __restrict__ cnt, int* __restrict__ offs)
{
    __shared__ int ssum[256];
    const int t = threadIdx.x;
    const int CH = 40;                       // 256*40 = 10240 >= N
    const int base = t * CH;
    int s = 0;
    for (int i = 0; i < CH; ++i) {
        int k = base + i;
        s += (k < N_NODES) ? cnt[k] : 0;
    }
    int own = s;
    ssum[t] = s;
    __syncthreads();
    #pragma unroll
    for (int d = 1; d < 256; d <<= 1) {
        int v = (t >= d) ? ssum[t - d] : 0;
        __syncthreads();
        ssum[t] += v;
        __syncthreads();
    }
    int acc = ssum[t] - own;                 // exclusive prefix
    for (int i = 0; i < CH; ++i) {
        int k = base + i;
        if (k < N_NODES) { offs[k] = acc; acc += cnt[k]; }
    }
    if (t == 255) offs[N_NODES] = acc;       // == E
}

__global__ __launch_bounds__(256)
void scatteridx_kernel(const int* __restrict__ dst, const int* __restrict__ offs,
                       int* __restrict__ cnt2, int* __restrict__ idx)
{
    int e = blockIdx.x * blockDim.x + threadIdx.x;
    if (e >= E_EDGES) return;
    int d = dst[e];
    int p = offs[d] + atomicAdd(&cnt2[d], 1);
    idx[p] = e;
}

// ---- gather: one wave per node ----
__global__ __launch_bounds__(256)
void gather_kernel(const int* __restrict__ offs, const int* __restrict__ idx,
                   const float* __restrict__ sc, const float* __restrict__ v,
                   float* __restrict__ out)
{
    const int lane = threadIdx.x & 63;
    const int wid  = threadIdx.x >> 6;
    const int n = blockIdx.x * 4 + wid;
    if (n >= N_NODES) return;
    const int s0 = offs[n], s1 = offs[n+1];

    // phase 1: per-head max
    const int i2 = lane >> 2, h = lane & 3;
    float m = -1e30f;
    for (int i = s0 + i2; i < s1; i += 16) {
        int eid = idx[i];
        m = fmaxf(m, sc[eid*4 + h]);
    }
    m = fmaxf(m, __shfl_xor(m, 4));
    m = fmaxf(m, __shfl_xor(m, 8));
    m = fmaxf(m, __shfl_xor(m, 16));
    m = fmaxf(m, __shfl_xor(m, 32));

    // phase 2: lanes j and j+32 (j<24) split the edge range
    const int j = lane & 31;
    const int half = lane >> 5;
    const int hd = (j < 24) ? (j / 6) : 0;
    float mh = __shfl(m, hd);

    float acc = 0.f, den = 0.f;
    if (j < 24) {
        for (int i = s0 + half; i < s1; i += 2) {
            int eid = idx[i];
            float ex = __expf(sc[eid*4 + hd] - mh);
            den += ex;
            acc = fmaf(ex, v[eid*24 + j], acc);
        }
    }
    acc += __shfl_xor(acc, 32);
    den += __shfl_xor(den, 32);
    if (half == 0 && j < 24) {
        out[n*24 + j] = (den > 0.f) ? (acc / den) : 0.f;
    }
}

extern "C" void kernel_launch(void* const* d_in, const int* in_sizes, int n_in,
                              void* d_out, int out_size, void* d_ws, size_t ws_size,
                              hipStream_t stream)
{
    const int*   src   = (const int*)d_in[0];
    const int*   dst   = (const int*)d_in[1];
    const float* basis = (const float*)d_in[2];
    const float* ef    = (const float*)d_in[3];
    const float* f     = (const float*)d_in[4];
    const float* W1    = (const float*)d_in[5];
    const float* b1    = (const float*)d_in[6];
    const float* W2    = (const float*)d_in[7];
    const float* b2    = (const float*)d_in[8];
    float* out = (float*)d_out;

    float*    v_buf  = (float*)d_ws;                              // E*24 f32
    float*    sc_buf = v_buf + (size_t)E_EDGES * 24;              // E*4 f32
    unsigned* w2p    = (unsigned*)(sc_buf + (size_t)E_EDGES * 4); // 24576 u32
    int*      cnt    = (int*)(w2p + 24576);                       // N
    int*      cnt2   = cnt + N_NODES;                             // N
    int*      offs   = cnt2 + N_NODES;                            // N+1
    int*      idx    = offs + (N_NODES + 1);                      // E

    (void)hipMemsetAsync(cnt, 0, (size_t)N_NODES * sizeof(int), stream);
    (void)hipMemsetAsync(cnt2, 0, (size_t)N_NODES * sizeof(int), stream);

    w2cvt_kernel<<<96, 256, 0, stream>>>(W2, w2p);

    fused_kernel<<<E_EDGES / 256, 1024, 0, stream>>>(src, basis, ef, f,
                                                     W1, b1, (const uint4*)w2p, b2,
                                                     v_buf, sc_buf);

    hist_kernel<<<(E_EDGES + 255) / 256, 256, 0, stream>>>(dst, cnt);
    scan_kernel<<<1, 256, 0, stream>>>(cnt, offs);
    scatteridx_kernel<<<(E_EDGES + 255) / 256, 256, 0, stream>>>(dst, offs, cnt2, idx);
    gather_kernel<<<(N_NODES + 3) / 4, 256, 0, stream>>>(offs, idx, sc_buf, v_buf, out);
}

// Round 14
// 251.260 us; speedup vs baseline: 1.0114x; 1.0114x over previous
//
#include <hip/hip_runtime.h>

#define E_EDGES 160000
#define N_NODES 10000

// 24^(-0.5)
#define TEMP 0.20412414523193154f

typedef __fp16 half2_t __attribute__((ext_vector_type(2)));
typedef __fp16 half8_t __attribute__((ext_vector_type(8)));
typedef float f32x4 __attribute__((ext_vector_type(4)));

__device__ __forceinline__ float fdot2(half2_t a, half2_t b, float c) {
#if __has_builtin(__builtin_amdgcn_fdot2)
    return __builtin_amdgcn_fdot2(a, b, c, false);
#else
    return fmaf((float)a.x, (float)b.x, fmaf((float)a.y, (float)b.y, c));
#endif
}
__device__ __forceinline__ half2_t pk(float a, float b) {
    return __builtin_amdgcn_cvt_pkrtz(a, b);
}

// W2 [768][64] f32 -> f16 in FRAGMENT order:
// u32 index u: tp=u&3, lane=(u>>2)&63, piece=(u>>8)&3, c=u>>10
// em=lane&15, quad=lane>>4; row=32c + (piece>>1)*16 + em; col=(piece&1)*32 + quad*8 + 2*tp
__global__ __launch_bounds__(256)
void w2cvt_kernel(const float* __restrict__ W2, unsigned* __restrict__ w2p)
{
    int u = blockIdx.x * blockDim.x + threadIdx.x;   // u < 24576
    int tp    = u & 3;
    int lane  = (u >> 2) & 63;
    int piece = (u >> 8) & 3;
    int c     = u >> 10;
    int em = lane & 15, quad = lane >> 4;
    int row = 32*c + ((piece >> 1) << 4) + em;
    int col = ((piece & 1) << 5) + quad*8 + 2*tp;
    union { half2_t h; unsigned v; } o;
    o.h.x = (__fp16)W2[row*64 + col];
    o.h.y = (__fp16)W2[row*64 + col + 1];
    w2p[u] = o.v;
}

// ---- fused per-edge kernel (R9 numerics), W2/W1/b2 staged in LDS ----
// Block = 1024 threads (16 waves), 16 edges/wave; LDS 107 KB -> 1 block/CU
// (= 4 waves/EU). amdgpu_waves_per_eu(4,4) PINS the occupancy target so the
// register allocator gets the full 512/4 = 128 VGPR budget. launch_bounds'
// 2nd arg is only a MINIMUM waves/EU -> compiler still targeted 8/EU and
// capped VGPR at 64, spilling ~220 MB (R12/R13 evidence).
__global__ __attribute__((amdgpu_flat_work_group_size(1024, 1024), amdgpu_waves_per_eu(4, 4)))
void fused_kernel(const int* __restrict__ src,
                  const float* __restrict__ basis, const float* __restrict__ efeat,
                  const float* __restrict__ f,
                  const float* __restrict__ W1, const float* __restrict__ b1,
                  const uint4* __restrict__ w2p, const float* __restrict__ b2,
                  float* __restrict__ v_out, float* __restrict__ sc_out)
{
    __shared__ __fp16 w2s[24*4*64*8];   // 96 KB, [c][piece][lane][8]
    __shared__ float  w1s[64*32];       // 8 KB
    __shared__ float  b2s[768];         // 3 KB

    const int tid  = threadIdx.x;
    const int lane = tid & 63;
    const int wid  = tid >> 6;
    const int em   = lane & 15;
    const int quad = lane >> 4;
    const int e = (blockIdx.x * 16 + wid) * 16 + em;

    // ---- stage weights (contiguous copies) ----
    {
        uint4* d4 = (uint4*)w2s;
        #pragma unroll
        for (int i = 0; i < 6; ++i) d4[i*1024 + tid] = w2p[i*1024 + tid];
        w1s[tid] = W1[tid];
        w1s[1024 + tid] = W1[1024 + tid];
        if (tid < 768) b2s[tid] = b2[tid];
    }
    __syncthreads();

    // ---- Phase A: h = relu(x @ W1^T + b1), fp32 (W1 via LDS broadcast) ----
    half8_t h_lo, h_hi;
    {
        float x[32];
        const float4* xv = (const float4*)(efeat + (size_t)e * 32);
        #pragma unroll
        for (int i = 0; i < 8; ++i) {
            float4 t = xv[i];
            x[4*i+0] = t.x; x[4*i+1] = t.y; x[4*i+2] = t.z; x[4*i+3] = t.w;
        }
        union { __fp16 h[8]; half8_t v; } lo, hi;
        #pragma unroll
        for (int t = 0; t < 8; ++t) {
            const int j0 = quad*8 + t;
            const int j1 = 32 + quad*8 + t;
            float a0 = b1[j0], a1 = b1[j1];
            const float* __restrict__ w0 = w1s + j0*32;
            const float* __restrict__ w1 = w1s + j1*32;
            #pragma unroll
            for (int i = 0; i < 32; ++i) {
                a0 = fmaf(w0[i], x[i], a0);
                a1 = fmaf(w1[i], x[i], a1);
            }
            lo.h[t] = (__fp16)fmaxf(a0, 0.0f);
            hi.h[t] = (__fp16)fmaxf(a1, 0.0f);
        }
        h_lo = lo.v; h_hi = hi.v;
    }

    // ---- Phase B: tmp2 quarter (mp = quad*4..+4), pairs (m', m'+16) ----
    half2_t t2[4][3];
    {
        float bas[18];
        const float2* bv = (const float2*)(basis + (size_t)e * 18);
        #pragma unroll
        for (int i = 0; i < 9; ++i) { float2 t = bv[i]; bas[2*i] = t.x; bas[2*i+1] = t.y; }
        const float* fp = f + (size_t)src[e] * 48 + quad*6;
        float fl[6], fh[6];
        #pragma unroll
        for (int i = 0; i < 3; ++i) {
            float2 a = *(const float2*)(fp + 2*i);      fl[2*i] = a.x; fl[2*i+1] = a.y;
            float2 b = *(const float2*)(fp + 24 + 2*i); fh[2*i] = b.x; fh[2*i+1] = b.y;
        }
        #pragma unroll
        for (int jj = 0; jj < 4; ++jj) {
            const int mr = (jj >> 1) * 3;
            const int rb = (jj & 1) * 3;
            #pragma unroll
            for (int d = 0; d < 3; ++d) {
                float lo = fmaf(fl[mr+0], bas[rb+d],
                           fmaf(fl[mr+1], bas[6+rb+d], fl[mr+2] * bas[12+rb+d]));
                float hi = fmaf(fh[mr+0], bas[rb+d],
                           fmaf(fh[mr+1], bas[6+rb+d], fh[mr+2] * bas[12+rb+d]));
                t2[jj][d] = pk(lo, hi);
            }
        }
    }

    // ---- Phase C: 24 conv rows; W2 fragments from LDS ----
    float kreg[8][3], vreg[8][3], sreg[4];
    #pragma unroll
    for (int c = 0; c < 24; ++c) {
        const __fp16* base = w2s + ((c*4)*64 + lane)*8;
        half8_t wa0 = *(const half8_t*)(base);
        half8_t wa1 = *(const half8_t*)(base + 64*8);
        half8_t wb0 = *(const half8_t*)(base + 2*64*8);
        half8_t wb1 = *(const half8_t*)(base + 3*64*8);
        float4 bb0 = *(const float4*)(b2s + 32*c + quad*4);
        float4 bb1 = *(const float4*)(b2s + 32*c + 16 + quad*4);

        f32x4 acc0 = {bb0.x, bb0.y, bb0.z, bb0.w};
        acc0 = __builtin_amdgcn_mfma_f32_16x16x32_f16(wa0, h_lo, acc0, 0, 0, 0);
        acc0 = __builtin_amdgcn_mfma_f32_16x16x32_f16(wa1, h_hi, acc0, 0, 0, 0);
        f32x4 acc1 = {bb1.x, bb1.y, bb1.z, bb1.w};
        acc1 = __builtin_amdgcn_mfma_f32_16x16x32_f16(wb0, h_lo, acc1, 0, 0, 0);
        acc1 = __builtin_amdgcn_mfma_f32_16x16x32_f16(wb1, h_hi, acc1, 0, 0, 0);

        float p0 = 0.f, p1 = 0.f, p2 = 0.f;
        #pragma unroll
        for (int r = 0; r < 4; ++r) {
            half2_t rp = pk(acc0[r], acc1[r]);
            p0 = fdot2(rp, t2[r][0], p0);
            p1 = fdot2(rp, t2[r][1], p1);
            p2 = fdot2(rp, t2[r][2], p2);
        }
        p0 += __shfl_xor(p0, 16); p0 += __shfl_xor(p0, 32);
        p1 += __shfl_xor(p1, 16); p1 += __shfl_xor(p1, 32);
        p2 += __shfl_xor(p2, 16); p2 += __shfl_xor(p2, 32);

        if (c < 8)       { kreg[c][0]=p0; kreg[c][1]=p1; kreg[c][2]=p2; }
        else if (c < 16) {
            float s_ = p0*kreg[c-8][0] + p1*kreg[c-8][1] + p2*kreg[c-8][2];
            if (((c)&1)==0) sreg[(c-8)>>1] = s_; else sreg[(c-8)>>1] += s_;
        }
        else             { vreg[c-16][0]=p0; vreg[c-16][1]=p1; vreg[c-16][2]=p2; }
    }

    // ---- Epilogue ----
    #pragma unroll
    for (int hh = 0; hh < 4; ++hh) {
        float s = sreg[hh] * TEMP;
        sreg[hh] = (s > 0.0f) ? s : 0.2f * s;
    }
    float* vb = v_out + (size_t)e * 24;
    if (quad == 3) {
        *(float4*)(sc_out + (size_t)e*4) = make_float4(sreg[0], sreg[1], sreg[2], sreg[3]);
    } else if (quad == 0) {
        *(float4*)(vb+0) = make_float4(vreg[0][0], vreg[0][1], vreg[0][2], vreg[1][0]);
        *(float4*)(vb+4) = make_float4(vreg[1][1], vreg[1][2], vreg[2][0], vreg[2][1]);
    } else if (quad == 1) {
        *(float4*)(vb+8)  = make_float4(vreg[2][2], vreg[3][0], vreg[3][1], vreg[3][2]);
        *(float4*)(vb+12) = make_float4(vreg[4][0], vreg[4][1], vreg[4][2], vreg[5][0]);
    } else {
        *(float4*)(vb+16) = make_float4(vreg[5][1], vreg[5][2], vreg[6][0], vreg[6][1]);
        *(float4*)(vb+20) = make_float4(vreg[6][2], vreg[7][0], vreg[7][1], vreg[7][2]);
    }
}

// ---- CSR build: histogram -> exclusive scan -> index scatter ----
__global__ __launch_bounds__(256)
void hist_kernel(const int* __restrict__ dst, int* __restrict__ cnt)
{
    int e = blockIdx.x * blockDim.x + threadIdx.x;
    if (e < E_EDGES) atomicAdd(&cnt[dst[e]], 1);
}

__global__ __launch_bounds__(256)
void scan_kernel(const int* __restrict__ cnt, int* __restrict__ offs)
{
    __shared__ int ssum[256];
    const int t = threadIdx.x;
    const int CH = 40;                       // 256*40 = 10240 >= N
    const int base = t * CH;
    int s = 0;
    for (int i = 0; i < CH; ++i) {
        int k = base + i;
        s += (k < N_NODES) ? cnt[k] : 0;
    }
    int own = s;
    ssum[t] = s;
    __syncthreads();
    #pragma unroll
    for (int d = 1; d < 256; d <<= 1) {
        int v = (t >= d) ? ssum[t - d] : 0;
        __syncthreads();
        ssum[t] += v;
        __syncthreads();
    }
    int acc = ssum[t] - own;                 // exclusive prefix
    for (int i = 0; i < CH; ++i) {
        int k = base + i;
        if (k < N_NODES) { offs[k] = acc; acc += cnt[k]; }
    }
    if (t == 255) offs[N_NODES] = acc;       // == E
}

__global__ __launch_bounds__(256)
void scatteridx_kernel(const int* __restrict__ dst, const int* __restrict__ offs,
                       int* __restrict__ cnt2, int* __restrict__ idx)
{
    int e = blockIdx.x * blockDim.x + threadIdx.x;
    if (e >= E_EDGES) return;
    int d = dst[e];
    int p = offs[d] + atomicAdd(&cnt2[d], 1);
    idx[p] = e;
}

// ---- gather: one wave per node ----
__global__ __launch_bounds__(256)
void gather_kernel(const int* __restrict__ offs, const int* __restrict__ idx,
                   const float* __restrict__ sc, const float* __restrict__ v,
                   float* __restrict__ out)
{
    const int lane = threadIdx.x & 63;
    const int wid  = threadIdx.x >> 6;
    const int n = blockIdx.x * 4 + wid;
    if (n >= N_NODES) return;
    const int s0 = offs[n], s1 = offs[n+1];

    // phase 1: per-head max
    const int i2 = lane >> 2, h = lane & 3;
    float m = -1e30f;
    for (int i = s0 + i2; i < s1; i += 16) {
        int eid = idx[i];
        m = fmaxf(m, sc[eid*4 + h]);
    }
    m = fmaxf(m, __shfl_xor(m, 4));
    m = fmaxf(m, __shfl_xor(m, 8));
    m = fmaxf(m, __shfl_xor(m, 16));
    m = fmaxf(m, __shfl_xor(m, 32));

    // phase 2: lanes j and j+32 (j<24) split the edge range
    const int j = lane & 31;
    const int half = lane >> 5;
    const int hd = (j < 24) ? (j / 6) : 0;
    float mh = __shfl(m, hd);

    float acc = 0.f, den = 0.f;
    if (j < 24) {
        for (int i = s0 + half; i < s1; i += 2) {
            int eid = idx[i];
            float ex = __expf(sc[eid*4 + hd] - mh);
            den += ex;
            acc = fmaf(ex, v[eid*24 + j], acc);
        }
    }
    acc += __shfl_xor(acc, 32);
    den += __shfl_xor(den, 32);
    if (half == 0 && j < 24) {
        out[n*24 + j] = (den > 0.f) ? (acc / den) : 0.f;
    }
}

extern "C" void kernel_launch(void* const* d_in, const int* in_sizes, int n_in,
                              void* d_out, int out_size, void* d_ws, size_t ws_size,
                              hipStream_t stream)
{
    const int*   src   = (const int*)d_in[0];
    const int*   dst   = (const int*)d_in[1];
    const float* basis = (const float*)d_in[2];
    const float* ef    = (const float*)d_in[3];
    const float* f     = (const float*)d_in[4];
    const float* W1    = (const float*)d_in[5];
    const float* b1    = (const float*)d_in[6];
    const float* W2    = (const float*)d_in[7];
    const float* b2    = (const float*)d_in[8];
    float* out = (float*)d_out;

    float*    v_buf  = (float*)d_ws;                              // E*24 f32
    float*    sc_buf = v_buf + (size_t)E_EDGES * 24;              // E*4 f32
    unsigned* w2p    = (unsigned*)(sc_buf + (size_t)E_EDGES * 4); // 24576 u32
    int*      cnt    = (int*)(w2p + 24576);                       // N
    int*      cnt2   = cnt + N_NODES;                             // N
    int*      offs   = cnt2 + N_NODES;                            // N+1
    int*      idx    = offs + (N_NODES + 1);                      // E

    (void)hipMemsetAsync(cnt, 0, (size_t)N_NODES * sizeof(int), stream);
    (void)hipMemsetAsync(cnt2, 0, (size_t)N_NODES * sizeof(int), stream);

    w2cvt_kernel<<<96, 256, 0, stream>>>(W2, w2p);

    fused_kernel<<<E_EDGES / 256, 1024, 0, stream>>>(src, basis, ef, f,
                                                     W1, b1, (const uint4*)w2p, b2,
                                                     v_buf, sc_buf);

    hist_kernel<<<(E_EDGES + 255) / 256, 256, 0, stream>>>(dst, cnt);
    scan_kernel<<<1, 256, 0, stream>>>(cnt, offs);
    scatteridx_kernel<<<(E_EDGES + 255) / 256, 256, 0, stream>>>(dst, offs, cnt2, idx);
    gather_kernel<<<(N_NODES + 3) / 4, 256, 0, stream>>>(offs, idx, sc_buf, v_buf, out);
}

// Round 15
// 209.224 us; speedup vs baseline: 1.2146x; 1.2009x over previous
//
#include <hip/hip_runtime.h>

#define E_EDGES 160000
#define N_NODES 10000

// 24^(-0.5)
#define TEMP 0.20412414523193154f

typedef __fp16 half2_t __attribute__((ext_vector_type(2)));
typedef __fp16 half8_t __attribute__((ext_vector_type(8)));
typedef float f32x4 __attribute__((ext_vector_type(4)));

__device__ __forceinline__ float fdot2(half2_t a, half2_t b, float c) {
#if __has_builtin(__builtin_amdgcn_fdot2)
    return __builtin_amdgcn_fdot2(a, b, c, false);
#else
    return fmaf((float)a.x, (float)b.x, fmaf((float)a.y, (float)b.y, c));
#endif
}
__device__ __forceinline__ half2_t pk(float a, float b) {
    return __builtin_amdgcn_cvt_pkrtz(a, b);
}

// W2 [768][64] f32 -> f16 in FRAGMENT order:
// u32 index u: tp=u&3, lane=(u>>2)&63, piece=(u>>8)&3, c=u>>10
// em=lane&15, quad=lane>>4; row=32c + (piece>>1)*16 + em; col=(piece&1)*32 + quad*8 + 2*tp
__global__ __launch_bounds__(256)
void w2cvt_kernel(const float* __restrict__ W2, unsigned* __restrict__ w2p)
{
    int u = blockIdx.x * blockDim.x + threadIdx.x;   // u < 24576
    int tp    = u & 3;
    int lane  = (u >> 2) & 63;
    int piece = (u >> 8) & 3;
    int c     = u >> 10;
    int em = lane & 15, quad = lane >> 4;
    int row = 32*c + ((piece >> 1) << 4) + em;
    int col = ((piece & 1) << 5) + quad*8 + 2*tp;
    union { half2_t h; unsigned v; } o;
    o.h.x = (__fp16)W2[row*64 + col];
    o.h.y = (__fp16)W2[row*64 + col + 1];
    w2p[u] = o.v;
}

// ---- fused per-edge kernel (R9 numerics): 256-thread blocks (proven no-spill
// VGPR regime), W2 staged in LDS in TWO passes (64 KB then 32 KB reusing the
// same buffer). 75 KB LDS -> 2 blocks/CU = 8 waves/CU. 1024-thread variants
// (R12-R14) pinned VGPR=64 and spilled ~220 MB -- do not use 1024 blocks.
__global__ __launch_bounds__(256, 2)
void fused_kernel(const int* __restrict__ src, const int* __restrict__ dst,
                  const float* __restrict__ basis, const float* __restrict__ efeat,
                  const float* __restrict__ f,
                  const float* __restrict__ W1, const float* __restrict__ b1,
                  const uint4* __restrict__ w2p, const float* __restrict__ b2,
                  float* __restrict__ v_out, float* __restrict__ sc_out,
                  int* __restrict__ cnt)
{
    __shared__ __fp16 w2s[16*4*64*8];   // 64 KB, pass1: [c<16][piece][lane][8]
    __shared__ float  w1s[64*32];       // 8 KB
    __shared__ float  b2s[768];         // 3 KB

    const int tid  = threadIdx.x;
    const int lane = tid & 63;
    const int wid  = tid >> 6;
    const int em   = lane & 15;
    const int quad = lane >> 4;
    const int e = (blockIdx.x * 4 + wid) * 16 + em;

    // ---- stage pass-1 weights: W2 rows for c=0..15 (4096 uint4), W1, b2 ----
    {
        uint4* d4 = (uint4*)w2s;
        #pragma unroll
        for (int i = 0; i < 16; ++i) d4[i*256 + tid] = w2p[i*256 + tid];
        float4* w14 = (float4*)w1s;
        const float4* W14 = (const float4*)W1;
        w14[tid] = W14[tid];
        w14[256 + tid] = W14[256 + tid];
        if (tid < 192) ((float4*)b2s)[tid] = ((const float4*)b2)[tid];
    }

    // ---- edge-degree histogram (folded-in hist_kernel) ----
    if (quad == 0) atomicAdd(&cnt[dst[e]], 1);

    // ---- Phase A: h = relu(x @ W1^T + b1), fp32 ----
    // (needs w1s staged; the barrier also covers w2s/b2s)
    __syncthreads();
    half8_t h_lo, h_hi;
    {
        float x[32];
        const float4* xv = (const float4*)(efeat + (size_t)e * 32);
        #pragma unroll
        for (int i = 0; i < 8; ++i) {
            float4 t = xv[i];
            x[4*i+0] = t.x; x[4*i+1] = t.y; x[4*i+2] = t.z; x[4*i+3] = t.w;
        }
        union { __fp16 h[8]; half8_t v; } lo, hi;
        #pragma unroll
        for (int t = 0; t < 8; ++t) {
            const int j0 = quad*8 + t;
            const int j1 = 32 + quad*8 + t;
            float a0 = b1[j0], a1 = b1[j1];
            const float* __restrict__ w0 = w1s + j0*32;
            const float* __restrict__ w1 = w1s + j1*32;
            #pragma unroll
            for (int i = 0; i < 32; ++i) {
                a0 = fmaf(w0[i], x[i], a0);
                a1 = fmaf(w1[i], x[i], a1);
            }
            lo.h[t] = (__fp16)fmaxf(a0, 0.0f);
            hi.h[t] = (__fp16)fmaxf(a1, 0.0f);
        }
        h_lo = lo.v; h_hi = hi.v;
    }

    // ---- Phase B: tmp2 quarter (mp = quad*4..+4), pairs (m', m'+16) ----
    half2_t t2[4][3];
    {
        float bas[18];
        const float2* bv = (const float2*)(basis + (size_t)e * 18);
        #pragma unroll
        for (int i = 0; i < 9; ++i) { float2 t = bv[i]; bas[2*i] = t.x; bas[2*i+1] = t.y; }
        const float* fp = f + (size_t)src[e] * 48 + quad*6;
        float fl[6], fh[6];
        #pragma unroll
        for (int i = 0; i < 3; ++i) {
            float2 a = *(const float2*)(fp + 2*i);      fl[2*i] = a.x; fl[2*i+1] = a.y;
            float2 b = *(const float2*)(fp + 24 + 2*i); fh[2*i] = b.x; fh[2*i+1] = b.y;
        }
        #pragma unroll
        for (int jj = 0; jj < 4; ++jj) {
            const int mr = (jj >> 1) * 3;
            const int rb = (jj & 1) * 3;
            #pragma unroll
            for (int d = 0; d < 3; ++d) {
                float lo = fmaf(fl[mr+0], bas[rb+d],
                           fmaf(fl[mr+1], bas[6+rb+d], fl[mr+2] * bas[12+rb+d]));
                float hi = fmaf(fh[mr+0], bas[rb+d],
                           fmaf(fh[mr+1], bas[6+rb+d], fh[mr+2] * bas[12+rb+d]));
                t2[jj][d] = pk(lo, hi);
            }
        }
    }

    // ---- Phase C pass 1: c = 0..15 (k rows + q rows -> scores) ----
    float kreg[8][3], sreg[4];
    #pragma unroll
    for (int c = 0; c < 16; ++c) {
        const __fp16* base = w2s + ((c*4)*64 + lane)*8;
        half8_t wa0 = *(const half8_t*)(base);
        half8_t wa1 = *(const half8_t*)(base + 64*8);
        half8_t wb0 = *(const half8_t*)(base + 2*64*8);
        half8_t wb1 = *(const half8_t*)(base + 3*64*8);
        float4 bb0 = *(const float4*)(b2s + 32*c + quad*4);
        float4 bb1 = *(const float4*)(b2s + 32*c + 16 + quad*4);

        f32x4 acc0 = {bb0.x, bb0.y, bb0.z, bb0.w};
        acc0 = __builtin_amdgcn_mfma_f32_16x16x32_f16(wa0, h_lo, acc0, 0, 0, 0);
        acc0 = __builtin_amdgcn_mfma_f32_16x16x32_f16(wa1, h_hi, acc0, 0, 0, 0);
        f32x4 acc1 = {bb1.x, bb1.y, bb1.z, bb1.w};
        acc1 = __builtin_amdgcn_mfma_f32_16x16x32_f16(wb0, h_lo, acc1, 0, 0, 0);
        acc1 = __builtin_amdgcn_mfma_f32_16x16x32_f16(wb1, h_hi, acc1, 0, 0, 0);

        float p0 = 0.f, p1 = 0.f, p2 = 0.f;
        #pragma unroll
        for (int r = 0; r < 4; ++r) {
            half2_t rp = pk(acc0[r], acc1[r]);
            p0 = fdot2(rp, t2[r][0], p0);
            p1 = fdot2(rp, t2[r][1], p1);
            p2 = fdot2(rp, t2[r][2], p2);
        }
        p0 += __shfl_xor(p0, 16); p0 += __shfl_xor(p0, 32);
        p1 += __shfl_xor(p1, 16); p1 += __shfl_xor(p1, 32);
        p2 += __shfl_xor(p2, 16); p2 += __shfl_xor(p2, 32);

        if (c < 8) { kreg[c][0]=p0; kreg[c][1]=p1; kreg[c][2]=p2; }
        else {
            float s_ = p0*kreg[c-8][0] + p1*kreg[c-8][1] + p2*kreg[c-8][2];
            if (((c)&1)==0) sreg[(c-8)>>1] = s_; else sreg[(c-8)>>1] += s_;
        }
    }

    // scores epilogue (registers only — safe before the barrier)
    #pragma unroll
    for (int hh = 0; hh < 4; ++hh) {
        float s = sreg[hh] * TEMP;
        sreg[hh] = (s > 0.0f) ? s : 0.2f * s;
    }
    if (quad == 3) {
        *(float4*)(sc_out + (size_t)e*4) = make_float4(sreg[0], sreg[1], sreg[2], sreg[3]);
    }

    // ---- stage pass-2 weights: W2 rows for c=16..23 (2048 uint4) ----
    __syncthreads();
    {
        uint4* d4 = (uint4*)w2s;
        #pragma unroll
        for (int i = 0; i < 8; ++i) d4[i*256 + tid] = w2p[4096 + i*256 + tid];
    }
    __syncthreads();

    // ---- Phase C pass 2: c = 16..23 (v rows) ----
    float vreg[8][3];
    #pragma unroll
    for (int cc = 0; cc < 8; ++cc) {
        const int c = 16 + cc;
        const __fp16* base = w2s + ((cc*4)*64 + lane)*8;
        half8_t wa0 = *(const half8_t*)(base);
        half8_t wa1 = *(const half8_t*)(base + 64*8);
        half8_t wb0 = *(const half8_t*)(base + 2*64*8);
        half8_t wb1 = *(const half8_t*)(base + 3*64*8);
        float4 bb0 = *(const float4*)(b2s + 32*c + quad*4);
        float4 bb1 = *(const float4*)(b2s + 32*c + 16 + quad*4);

        f32x4 acc0 = {bb0.x, bb0.y, bb0.z, bb0.w};
        acc0 = __builtin_amdgcn_mfma_f32_16x16x32_f16(wa0, h_lo, acc0, 0, 0, 0);
        acc0 = __builtin_amdgcn_mfma_f32_16x16x32_f16(wa1, h_hi, acc0, 0, 0, 0);
        f32x4 acc1 = {bb0.x, bb0.y, bb0.z, bb0.w};   // placeholder, overwritten below
        acc1 = (f32x4){bb1.x, bb1.y, bb1.z, bb1.w};
        acc1 = __builtin_amdgcn_mfma_f32_16x16x32_f16(wb0, h_lo, acc1, 0, 0, 0);
        acc1 = __builtin_amdgcn_mfma_f32_16x16x32_f16(wb1, h_hi, acc1, 0, 0, 0);

        float p0 = 0.f, p1 = 0.f, p2 = 0.f;
        #pragma unroll
        for (int r = 0; r < 4; ++r) {
            half2_t rp = pk(acc0[r], acc1[r]);
            p0 = fdot2(rp, t2[r][0], p0);
            p1 = fdot2(rp, t2[r][1], p1);
            p2 = fdot2(rp, t2[r][2], p2);
        }
        p0 += __shfl_xor(p0, 16); p0 += __shfl_xor(p0, 32);
        p1 += __shfl_xor(p1, 16); p1 += __shfl_xor(p1, 32);
        p2 += __shfl_xor(p2, 16); p2 += __shfl_xor(p2, 32);

        vreg[cc][0]=p0; vreg[cc][1]=p1; vreg[cc][2]=p2;
    }

    // ---- v epilogue ----
    float* vb = v_out + (size_t)e * 24;
    if (quad == 0) {
        *(float4*)(vb+0) = make_float4(vreg[0][0], vreg[0][1], vreg[0][2], vreg[1][0]);
        *(float4*)(vb+4) = make_float4(vreg[1][1], vreg[1][2], vreg[2][0], vreg[2][1]);
    } else if (quad == 1) {
        *(float4*)(vb+8)  = make_float4(vreg[2][2], vreg[3][0], vreg[3][1], vreg[3][2]);
        *(float4*)(vb+12) = make_float4(vreg[4][0], vreg[4][1], vreg[4][2], vreg[5][0]);
    } else if (quad == 2) {
        *(float4*)(vb+16) = make_float4(vreg[5][1], vreg[5][2], vreg[6][0], vreg[6][1]);
        *(float4*)(vb+20) = make_float4(vreg[6][2], vreg[7][0], vreg[7][1], vreg[7][2]);
    }
}

// ---- CSR build: exclusive scan -> index scatter ----
__global__ __launch_bounds__(256)
void scan_kernel(const int* __restrict__ cnt, int* __restrict__ offs)
{
    __shared__ int ssum[256];
    const int t = threadIdx.x;
    const int CH = 40;                       // 256*40 = 10240 >= N
    const int base = t * CH;
    int s = 0;
    for (int i = 0; i < CH; ++i) {
        int k = base + i;
        s += (k < N_NODES) ? cnt[k] : 0;
    }
    int own = s;
    ssum[t] = s;
    __syncthreads();
    #pragma unroll
    for (int d = 1; d < 256; d <<= 1) {
        int v = (t >= d) ? ssum[t - d] : 0;
        __syncthreads();
        ssum[t] += v;
        __syncthreads();
    }
    int acc = ssum[t] - own;                 // exclusive prefix
    for (int i = 0; i < CH; ++i) {
        int k = base + i;
        if (k < N_NODES) { offs[k] = acc; acc += cnt[k]; }
    }
    if (t == 255) offs[N_NODES] = acc;       // == E
}

__global__ __launch_bounds__(256)
void scatteridx_kernel(const int* __restrict__ dst, const int* __restrict__ offs,
                       int* __restrict__ cnt2, int* __restrict__ idx)
{
    int e = blockIdx.x * blockDim.x + threadIdx.x;
    if (e >= E_EDGES) return;
    int d = dst[e];
    int p = offs[d] + atomicAdd(&cnt2[d], 1);
    idx[p] = e;
}

// ---- gather: one wave per node ----
__global__ __launch_bounds__(256)
void gather_kernel(const int* __restrict__ offs, const int* __restrict__ idx,
                   const float* __restrict__ sc, const float* __restrict__ v,
                   float* __restrict__ out)
{
    const int lane = threadIdx.x & 63;
    const int wid  = threadIdx.x >> 6;
    const int n = blockIdx.x * 4 + wid;
    if (n >= N_NODES) return;
    const int s0 = offs[n], s1 = offs[n+1];

    // phase 1: per-head max
    const int i2 = lane >> 2, h = lane & 3;
    float m = -1e30f;
    for (int i = s0 + i2; i < s1; i += 16) {
        int eid = idx[i];
        m = fmaxf(m, sc[eid*4 + h]);
    }
    m = fmaxf(m, __shfl_xor(m, 4));
    m = fmaxf(m, __shfl_xor(m, 8));
    m = fmaxf(m, __shfl_xor(m, 16));
    m = fmaxf(m, __shfl_xor(m, 32));

    // phase 2: lanes j and j+32 (j<24) split the edge range
    const int j = lane & 31;
    const int half = lane >> 5;
    const int hd = (j < 24) ? (j / 6) : 0;
    float mh = __shfl(m, hd);

    float acc = 0.f, den = 0.f;
    if (j < 24) {
        for (int i = s0 + half; i < s1; i += 2) {
            int eid = idx[i];
            float ex = __expf(sc[eid*4 + hd] - mh);
            den += ex;
            acc = fmaf(ex, v[eid*24 + j], acc);
        }
    }
    acc += __shfl_xor(acc, 32);
    den += __shfl_xor(den, 32);
    if (half == 0 && j < 24) {
        out[n*24 + j] = (den > 0.f) ? (acc / den) : 0.f;
    }
}

extern "C" void kernel_launch(void* const* d_in, const int* in_sizes, int n_in,
                              void* d_out, int out_size, void* d_ws, size_t ws_size,
                              hipStream_t stream)
{
    const int*   src   = (const int*)d_in[0];
    const int*   dst   = (const int*)d_in[1];
    const float* basis = (const float*)d_in[2];
    const float* ef    = (const float*)d_in[3];
    const float* f     = (const float*)d_in[4];
    const float* W1    = (const float*)d_in[5];
    const float* b1    = (const float*)d_in[6];
    const float* W2    = (const float*)d_in[7];
    const float* b2    = (const float*)d_in[8];
    float* out = (float*)d_out;

    float*    v_buf  = (float*)d_ws;                              // E*24 f32
    float*    sc_buf = v_buf + (size_t)E_EDGES * 24;              // E*4 f32
    unsigned* w2p    = (unsigned*)(sc_buf + (size_t)E_EDGES * 4); // 24576 u32
    int*      cnt    = (int*)(w2p + 24576);                       // N
    int*      cnt2   = cnt + N_NODES;                             // N
    int*      offs   = cnt2 + N_NODES;                            // N+1
    int*      idx    = offs + (N_NODES + 1);                      // E

    (void)hipMemsetAsync(cnt, 0, (size_t)N_NODES * sizeof(int), stream);
    (void)hipMemsetAsync(cnt2, 0, (size_t)N_NODES * sizeof(int), stream);

    w2cvt_kernel<<<96, 256, 0, stream>>>(W2, w2p);

    fused_kernel<<<E_EDGES / 64, 256, 0, stream>>>(src, dst, basis, ef, f,
                                                   W1, b1, (const uint4*)w2p, b2,
                                                   v_buf, sc_buf, cnt);

    scan_kernel<<<1, 256, 0, stream>>>(cnt, offs);
    scatteridx_kernel<<<(E_EDGES + 255) / 256, 256, 0, stream>>>(dst, offs, cnt2, idx);
    gather_kernel<<<(N_NODES + 3) / 4, 256, 0, stream>>>(offs, idx, sc_buf, v_buf, out);
}

// Round 16
// 197.405 us; speedup vs baseline: 1.2873x; 1.0599x over previous
//
#include <hip/hip_runtime.h>

#define E_EDGES 160000
#define N_NODES 10000

// 24^(-0.5)
#define TEMP 0.20412414523193154f

typedef __fp16 half2_t __attribute__((ext_vector_type(2)));
typedef __fp16 half8_t __attribute__((ext_vector_type(8)));
typedef float f32x4 __attribute__((ext_vector_type(4)));

__device__ __forceinline__ float fdot2(half2_t a, half2_t b, float c) {
#if __has_builtin(__builtin_amdgcn_fdot2)
    return __builtin_amdgcn_fdot2(a, b, c, false);
#else
    return fmaf((float)a.x, (float)b.x, fmaf((float)a.y, (float)b.y, c));
#endif
}
__device__ __forceinline__ half2_t pk(float a, float b) {
    return __builtin_amdgcn_cvt_pkrtz(a, b);
}

// W2 [768][64] f32 -> f16 in FRAGMENT order:
// u32 index u: tp=u&3, lane=(u>>2)&63, piece=(u>>8)&3, c=u>>10
// em=lane&15, quad=lane>>4; row=32c + (piece>>1)*16 + em; col=(piece&1)*32 + quad*8 + 2*tp
__global__ __launch_bounds__(256)
void w2cvt_kernel(const float* __restrict__ W2, unsigned* __restrict__ w2p)
{
    int u = blockIdx.x * blockDim.x + threadIdx.x;   // u < 24576
    int tp    = u & 3;
    int lane  = (u >> 2) & 63;
    int piece = (u >> 8) & 3;
    int c     = u >> 10;
    int em = lane & 15, quad = lane >> 4;
    int row = 32*c + ((piece >> 1) << 4) + em;
    int col = ((piece & 1) << 5) + quad*8 + 2*tp;
    union { half2_t h; unsigned v; } o;
    o.h.x = (__fp16)W2[row*64 + col];
    o.h.y = (__fp16)W2[row*64 + col + 1];
    w2p[u] = o.v;
}

// Compute one 8-c-row group (needs w2s staged with that group's fragments).
// cg = c - cbase in [0,8). Returns p0,p1,p2 per c into the out array slot.
#define CONV_GROUP(cbase, OUT) \
    _Pragma("unroll") \
    for (int cg = 0; cg < 8; ++cg) { \
        const int c = (cbase) + cg; \
        const __fp16* base = w2s + ((cg*4)*64 + lane)*8; \
        half8_t wa0 = *(const half8_t*)(base); \
        half8_t wa1 = *(const half8_t*)(base + 64*8); \
        half8_t wb0 = *(const half8_t*)(base + 2*64*8); \
        half8_t wb1 = *(const half8_t*)(base + 3*64*8); \
        float4 bb0 = *(const float4*)(b2s + 32*c + quad*4); \
        float4 bb1 = *(const float4*)(b2s + 32*c + 16 + quad*4); \
        f32x4 acc0 = {bb0.x, bb0.y, bb0.z, bb0.w}; \
        acc0 = __builtin_amdgcn_mfma_f32_16x16x32_f16(wa0, h_lo, acc0, 0, 0, 0); \
        acc0 = __builtin_amdgcn_mfma_f32_16x16x32_f16(wa1, h_hi, acc0, 0, 0, 0); \
        f32x4 acc1 = {bb1.x, bb1.y, bb1.z, bb1.w}; \
        acc1 = __builtin_amdgcn_mfma_f32_16x16x32_f16(wb0, h_lo, acc1, 0, 0, 0); \
        acc1 = __builtin_amdgcn_mfma_f32_16x16x32_f16(wb1, h_hi, acc1, 0, 0, 0); \
        float p0 = 0.f, p1 = 0.f, p2 = 0.f; \
        _Pragma("unroll") \
        for (int r = 0; r < 4; ++r) { \
            half2_t rp = pk(acc0[r], acc1[r]); \
            p0 = fdot2(rp, t2[r][0], p0); \
            p1 = fdot2(rp, t2[r][1], p1); \
            p2 = fdot2(rp, t2[r][2], p2); \
        } \
        p0 += __shfl_xor(p0, 16); p0 += __shfl_xor(p0, 32); \
        p1 += __shfl_xor(p1, 16); p1 += __shfl_xor(p1, 32); \
        p2 += __shfl_xor(p2, 16); p2 += __shfl_xor(p2, 32); \
        OUT; \
    }

#define STAGE_W2(group) { \
    uint4* d4 = (uint4*)w2s; \
    _Pragma("unroll") \
    for (int i = 0; i < 8; ++i) d4[i*256 + tid] = w2p[(group)*2048 + i*256 + tid]; \
}

// ---- fused per-edge kernel (R9 numerics): 256-thread blocks, W2 staged in
// LDS in THREE 32-KB passes (k, q, v row groups). LDS 43 KB -> 3 blocks/CU.
// 1024-thread variants (R12-R14) pinned VGPR=64 and spilled -- keep 256.
__global__ __launch_bounds__(256, 3)
void fused_kernel(const int* __restrict__ src, const int* __restrict__ dst,
                  const float* __restrict__ basis, const float* __restrict__ efeat,
                  const float* __restrict__ f,
                  const float* __restrict__ W1, const float* __restrict__ b1,
                  const uint4* __restrict__ w2p, const float* __restrict__ b2,
                  float* __restrict__ v_out, float* __restrict__ sc_out,
                  int* __restrict__ cnt)
{
    __shared__ __fp16 w2s[8*4*64*8];    // 32 KB, one 8-c-row group
    __shared__ float  w1s[64*32];       // 8 KB
    __shared__ float  b2s[768];         // 3 KB

    const int tid  = threadIdx.x;
    const int lane = tid & 63;
    const int wid  = tid >> 6;
    const int em   = lane & 15;
    const int quad = lane >> 4;
    const int e = (blockIdx.x * 4 + wid) * 16 + em;

    // ---- stage pass-1 (k rows c=0..7) + W1 + b2 ----
    STAGE_W2(0);
    {
        float4* w14 = (float4*)w1s;
        const float4* W14 = (const float4*)W1;
        w14[tid] = W14[tid];
        w14[256 + tid] = W14[256 + tid];
        if (tid < 192) ((float4*)b2s)[tid] = ((const float4*)b2)[tid];
    }

    // ---- edge-degree histogram (folded-in) ----
    if (quad == 0) atomicAdd(&cnt[dst[e]], 1);

    __syncthreads();

    // ---- Phase A: h = relu(x @ W1^T + b1), fp32 ----
    half8_t h_lo, h_hi;
    {
        float x[32];
        const float4* xv = (const float4*)(efeat + (size_t)e * 32);
        #pragma unroll
        for (int i = 0; i < 8; ++i) {
            float4 t = xv[i];
            x[4*i+0] = t.x; x[4*i+1] = t.y; x[4*i+2] = t.z; x[4*i+3] = t.w;
        }
        union { __fp16 h[8]; half8_t v; } lo, hi;
        #pragma unroll
        for (int t = 0; t < 8; ++t) {
            const int j0 = quad*8 + t;
            const int j1 = 32 + quad*8 + t;
            float a0 = b1[j0], a1 = b1[j1];
            const float* __restrict__ w0 = w1s + j0*32;
            const float* __restrict__ w1 = w1s + j1*32;
            #pragma unroll
            for (int i = 0; i < 32; ++i) {
                a0 = fmaf(w0[i], x[i], a0);
                a1 = fmaf(w1[i], x[i], a1);
            }
            lo.h[t] = (__fp16)fmaxf(a0, 0.0f);
            hi.h[t] = (__fp16)fmaxf(a1, 0.0f);
        }
        h_lo = lo.v; h_hi = hi.v;
    }

    // ---- Phase B: tmp2 quarter (mp = quad*4..+4), pairs (m', m'+16) ----
    half2_t t2[4][3];
    {
        float bas[18];
        const float2* bv = (const float2*)(basis + (size_t)e * 18);
        #pragma unroll
        for (int i = 0; i < 9; ++i) { float2 t = bv[i]; bas[2*i] = t.x; bas[2*i+1] = t.y; }
        const float* fp = f + (size_t)src[e] * 48 + quad*6;
        float fl[6], fh[6];
        #pragma unroll
        for (int i = 0; i < 3; ++i) {
            float2 a = *(const float2*)(fp + 2*i);      fl[2*i] = a.x; fl[2*i+1] = a.y;
            float2 b = *(const float2*)(fp + 24 + 2*i); fh[2*i] = b.x; fh[2*i+1] = b.y;
        }
        #pragma unroll
        for (int jj = 0; jj < 4; ++jj) {
            const int mr = (jj >> 1) * 3;
            const int rb = (jj & 1) * 3;
            #pragma unroll
            for (int d = 0; d < 3; ++d) {
                float lo = fmaf(fl[mr+0], bas[rb+d],
                           fmaf(fl[mr+1], bas[6+rb+d], fl[mr+2] * bas[12+rb+d]));
                float hi = fmaf(fh[mr+0], bas[rb+d],
                           fmaf(fh[mr+1], bas[6+rb+d], fh[mr+2] * bas[12+rb+d]));
                t2[jj][d] = pk(lo, hi);
            }
        }
    }

    // ---- pass 1: k rows (c = 0..7) ----
    float kreg[8][3];
    CONV_GROUP(0, { kreg[cg][0]=p0; kreg[cg][1]=p1; kreg[cg][2]=p2; });

    // ---- pass 2: q rows (c = 8..15) -> scores ----
    __syncthreads();
    STAGE_W2(1);
    __syncthreads();
    float sreg[4];
    CONV_GROUP(8, {
        float s_ = p0*kreg[cg][0] + p1*kreg[cg][1] + p2*kreg[cg][2];
        if ((cg & 1) == 0) sreg[cg>>1] = s_; else sreg[cg>>1] += s_;
    });

    #pragma unroll
    for (int hh = 0; hh < 4; ++hh) {
        float s = sreg[hh] * TEMP;
        sreg[hh] = (s > 0.0f) ? s : 0.2f * s;
    }
    if (quad == 3) {
        *(float4*)(sc_out + (size_t)e*4) = make_float4(sreg[0], sreg[1], sreg[2], sreg[3]);
    }

    // ---- pass 3: v rows (c = 16..23) ----
    __syncthreads();
    STAGE_W2(2);
    __syncthreads();
    float vreg[8][3];
    CONV_GROUP(16, { vreg[cg][0]=p0; vreg[cg][1]=p1; vreg[cg][2]=p2; });

    float* vb = v_out + (size_t)e * 24;
    if (quad == 0) {
        *(float4*)(vb+0) = make_float4(vreg[0][0], vreg[0][1], vreg[0][2], vreg[1][0]);
        *(float4*)(vb+4) = make_float4(vreg[1][1], vreg[1][2], vreg[2][0], vreg[2][1]);
    } else if (quad == 1) {
        *(float4*)(vb+8)  = make_float4(vreg[2][2], vreg[3][0], vreg[3][1], vreg[3][2]);
        *(float4*)(vb+12) = make_float4(vreg[4][0], vreg[4][1], vreg[4][2], vreg[5][0]);
    } else if (quad == 2) {
        *(float4*)(vb+16) = make_float4(vreg[5][1], vreg[5][2], vreg[6][0], vreg[6][1]);
        *(float4*)(vb+20) = make_float4(vreg[6][2], vreg[7][0], vreg[7][1], vreg[7][2]);
    }
}

// ---- CSR build: exclusive scan -> index scatter ----
__global__ __launch_bounds__(256)
void scan_kernel(const int* __restrict__ cnt, int* __restrict__ offs)
{
    __shared__ int ssum[256];
    const int t = threadIdx.x;
    const int CH = 40;                       // 256*40 = 10240 >= N
    const int base = t * CH;
    int s = 0;
    for (int i = 0; i < CH; ++i) {
        int k = base + i;
        s += (k < N_NODES) ? cnt[k] : 0;
    }
    int own = s;
    ssum[t] = s;
    __syncthreads();
    #pragma unroll
    for (int d = 1; d < 256; d <<= 1) {
        int v = (t >= d) ? ssum[t - d] : 0;
        __syncthreads();
        ssum[t] += v;
        __syncthreads();
    }
    int acc = ssum[t] - own;                 // exclusive prefix
    for (int i = 0; i < CH; ++i) {
        int k = base + i;
        if (k < N_NODES) { offs[k] = acc; acc += cnt[k]; }
    }
    if (t == 255) offs[N_NODES] = acc;       // == E
}

__global__ __launch_bounds__(256)
void scatteridx_kernel(const int* __restrict__ dst, const int* __restrict__ offs,
                       int* __restrict__ cnt2, int* __restrict__ idx)
{
    int e = blockIdx.x * blockDim.x + threadIdx.x;
    if (e >= E_EDGES) return;
    int d = dst[e];
    int p = offs[d] + atomicAdd(&cnt2[d], 1);
    idx[p] = e;
}

// ---- gather: one wave per node ----
__global__ __launch_bounds__(256)
void gather_kernel(const int* __restrict__ offs, const int* __restrict__ idx,
                   const float* __restrict__ sc, const float* __restrict__ v,
                   float* __restrict__ out)
{
    const int lane = threadIdx.x & 63;
    const int wid  = threadIdx.x >> 6;
    const int n = blockIdx.x * 4 + wid;
    if (n >= N_NODES) return;
    const int s0 = offs[n], s1 = offs[n+1];

    // phase 1: per-head max
    const int i2 = lane >> 2, h = lane & 3;
    float m = -1e30f;
    for (int i = s0 + i2; i < s1; i += 16) {
        int eid = idx[i];
        m = fmaxf(m, sc[eid*4 + h]);
    }
    m = fmaxf(m, __shfl_xor(m, 4));
    m = fmaxf(m, __shfl_xor(m, 8));
    m = fmaxf(m, __shfl_xor(m, 16));
    m = fmaxf(m, __shfl_xor(m, 32));

    // phase 2: lanes j and j+32 (j<24) split the edge range
    const int j = lane & 31;
    const int half = lane >> 5;
    const int hd = (j < 24) ? (j / 6) : 0;
    float mh = __shfl(m, hd);

    float acc = 0.f, den = 0.f;
    if (j < 24) {
        for (int i = s0 + half; i < s1; i += 2) {
            int eid = idx[i];
            float ex = __expf(sc[eid*4 + hd] - mh);
            den += ex;
            acc = fmaf(ex, v[eid*24 + j], acc);
        }
    }
    acc += __shfl_xor(acc, 32);
    den += __shfl_xor(den, 32);
    if (half == 0 && j < 24) {
        out[n*24 + j] = (den > 0.f) ? (acc / den) : 0.f;
    }
}

extern "C" void kernel_launch(void* const* d_in, const int* in_sizes, int n_in,
                              void* d_out, int out_size, void* d_ws, size_t ws_size,
                              hipStream_t stream)
{
    const int*   src   = (const int*)d_in[0];
    const int*   dst   = (const int*)d_in[1];
    const float* basis = (const float*)d_in[2];
    const float* ef    = (const float*)d_in[3];
    const float* f     = (const float*)d_in[4];
    const float* W1    = (const float*)d_in[5];
    const float* b1    = (const float*)d_in[6];
    const float* W2    = (const float*)d_in[7];
    const float* b2    = (const float*)d_in[8];
    float* out = (float*)d_out;

    float*    v_buf  = (float*)d_ws;                              // E*24 f32
    float*    sc_buf = v_buf + (size_t)E_EDGES * 24;              // E*4 f32
    unsigned* w2p    = (unsigned*)(sc_buf + (size_t)E_EDGES * 4); // 24576 u32
    int*      cnt    = (int*)(w2p + 24576);                       // N
    int*      cnt2   = cnt + N_NODES;                             // N  (adjacent -> one memset)
    int*      offs   = cnt2 + N_NODES;                            // N+1
    int*      idx    = offs + (N_NODES + 1);                      // E

    (void)hipMemsetAsync(cnt, 0, (size_t)(2 * N_NODES) * sizeof(int), stream);

    w2cvt_kernel<<<96, 256, 0, stream>>>(W2, w2p);

    fused_kernel<<<E_EDGES / 64, 256, 0, stream>>>(src, dst, basis, ef, f,
                                                   W1, b1, (const uint4*)w2p, b2,
                                                   v_buf, sc_buf, cnt);

    scan_kernel<<<1, 256, 0, stream>>>(cnt, offs);
    scatteridx_kernel<<<(E_EDGES + 255) / 256, 256, 0, stream>>>(dst, offs, cnt2, idx);
    gather_kernel<<<(N_NODES + 3) / 4, 256, 0, stream>>>(offs, idx, sc_buf, v_buf, out);
}

// Round 17
// 164.906 us; speedup vs baseline: 1.5410x; 1.1971x over previous
//
#include <hip/hip_runtime.h>

#define E_EDGES 160000
#define N_NODES 10000
#define SLOTS   64      // per-node edge bucket capacity (mean deg 16, 12-sigma safe)

// 24^(-0.5)
#define TEMP 0.20412414523193154f

typedef __fp16 half2_t __attribute__((ext_vector_type(2)));
typedef __fp16 half8_t __attribute__((ext_vector_type(8)));
typedef float f32x4 __attribute__((ext_vector_type(4)));

__device__ __forceinline__ float fdot2(half2_t a, half2_t b, float c) {
#if __has_builtin(__builtin_amdgcn_fdot2)
    return __builtin_amdgcn_fdot2(a, b, c, false);
#else
    return fmaf((float)a.x, (float)b.x, fmaf((float)a.y, (float)b.y, c));
#endif
}
__device__ __forceinline__ half2_t pk(float a, float b) {
    return __builtin_amdgcn_cvt_pkrtz(a, b);
}

// prep: W2 [768][64] f32 -> f16 fragment order, AND zero cnt. One dispatch.
__global__ __launch_bounds__(256)
void prep_kernel(const float* __restrict__ W2, unsigned* __restrict__ w2p,
                 int* __restrict__ cnt)
{
    int u = blockIdx.x * blockDim.x + threadIdx.x;   // u < 24576
    if (u < N_NODES) cnt[u] = 0;
    int tp    = u & 3;
    int lane  = (u >> 2) & 63;
    int piece = (u >> 8) & 3;
    int c     = u >> 10;
    int em = lane & 15, quad = lane >> 4;
    int row = 32*c + ((piece >> 1) << 4) + em;
    int col = ((piece & 1) << 5) + quad*8 + 2*tp;
    union { half2_t h; unsigned v; } o;
    o.h.x = (__fp16)W2[row*64 + col];
    o.h.y = (__fp16)W2[row*64 + col + 1];
    w2p[u] = o.v;
}

#define CONV_GROUP(cbase, OUT) \
    _Pragma("unroll") \
    for (int cg = 0; cg < 8; ++cg) { \
        const int c = (cbase) + cg; \
        const __fp16* base = w2s + ((cg*4)*64 + lane)*8; \
        half8_t wa0 = *(const half8_t*)(base); \
        half8_t wa1 = *(const half8_t*)(base + 64*8); \
        half8_t wb0 = *(const half8_t*)(base + 2*64*8); \
        half8_t wb1 = *(const half8_t*)(base + 3*64*8); \
        float4 bb0 = *(const float4*)(b2s + 32*c + quad*4); \
        float4 bb1 = *(const float4*)(b2s + 32*c + 16 + quad*4); \
        f32x4 acc0 = {bb0.x, bb0.y, bb0.z, bb0.w}; \
        acc0 = __builtin_amdgcn_mfma_f32_16x16x32_f16(wa0, h_lo, acc0, 0, 0, 0); \
        acc0 = __builtin_amdgcn_mfma_f32_16x16x32_f16(wa1, h_hi, acc0, 0, 0, 0); \
        f32x4 acc1 = {bb1.x, bb1.y, bb1.z, bb1.w}; \
        acc1 = __builtin_amdgcn_mfma_f32_16x16x32_f16(wb0, h_lo, acc1, 0, 0, 0); \
        acc1 = __builtin_amdgcn_mfma_f32_16x16x32_f16(wb1, h_hi, acc1, 0, 0, 0); \
        float p0 = 0.f, p1 = 0.f, p2 = 0.f; \
        _Pragma("unroll") \
        for (int r = 0; r < 4; ++r) { \
            half2_t rp = pk(acc0[r], acc1[r]); \
            p0 = fdot2(rp, t2[r][0], p0); \
            p1 = fdot2(rp, t2[r][1], p1); \
            p2 = fdot2(rp, t2[r][2], p2); \
        } \
        p0 += __shfl_xor(p0, 16); p0 += __shfl_xor(p0, 32); \
        p1 += __shfl_xor(p1, 16); p1 += __shfl_xor(p1, 32); \
        p2 += __shfl_xor(p2, 16); p2 += __shfl_xor(p2, 32); \
        OUT; \
    }

#define STAGE_W2(group) { \
    uint4* d4 = (uint4*)w2s; \
    _Pragma("unroll") \
    for (int i = 0; i < 8; ++i) d4[i*256 + tid] = w2p[(group)*2048 + i*256 + tid]; \
}

// ---- fused per-edge kernel (R16-proven): 256-thread blocks, 3-pass W2 LDS
// staging (32 KB/pass), 43 KB LDS -> 3 blocks/CU. Epilogue also places the
// edge into its dst node's static bucket (replaces hist+scan+scatteridx).
__global__ __launch_bounds__(256, 3)
void fused_kernel(const int* __restrict__ src, const int* __restrict__ dst,
                  const float* __restrict__ basis, const float* __restrict__ efeat,
                  const float* __restrict__ f,
                  const float* __restrict__ W1, const float* __restrict__ b1,
                  const uint4* __restrict__ w2p, const float* __restrict__ b2,
                  float* __restrict__ v_out, float* __restrict__ sc_out,
                  int* __restrict__ cnt, int* __restrict__ idx)
{
    __shared__ __fp16 w2s[8*4*64*8];    // 32 KB, one 8-c-row group
    __shared__ float  w1s[64*32];       // 8 KB
    __shared__ float  b2s[768];         // 3 KB

    const int tid  = threadIdx.x;
    const int lane = tid & 63;
    const int wid  = tid >> 6;
    const int em   = lane & 15;
    const int quad = lane >> 4;
    const int e = (blockIdx.x * 4 + wid) * 16 + em;

    // ---- stage pass-1 (k rows c=0..7) + W1 + b2 ----
    STAGE_W2(0);
    {
        float4* w14 = (float4*)w1s;
        const float4* W14 = (const float4*)W1;
        w14[tid] = W14[tid];
        w14[256 + tid] = W14[256 + tid];
        if (tid < 192) ((float4*)b2s)[tid] = ((const float4*)b2)[tid];
    }

    // ---- CSR-free bucket placement: one atomic per edge ----
    if (quad == 0) {
        int dn = dst[e];
        int p = atomicAdd(&cnt[dn], 1);
        if (p < SLOTS) idx[dn*SLOTS + p] = e;
    }

    __syncthreads();

    // ---- Phase A: h = relu(x @ W1^T + b1), fp32 ----
    half8_t h_lo, h_hi;
    {
        float x[32];
        const float4* xv = (const float4*)(efeat + (size_t)e * 32);
        #pragma unroll
        for (int i = 0; i < 8; ++i) {
            float4 t = xv[i];
            x[4*i+0] = t.x; x[4*i+1] = t.y; x[4*i+2] = t.z; x[4*i+3] = t.w;
        }
        union { __fp16 h[8]; half8_t v; } lo, hi;
        #pragma unroll
        for (int t = 0; t < 8; ++t) {
            const int j0 = quad*8 + t;
            const int j1 = 32 + quad*8 + t;
            float a0 = b1[j0], a1 = b1[j1];
            const float* __restrict__ w0 = w1s + j0*32;
            const float* __restrict__ w1 = w1s + j1*32;
            #pragma unroll
            for (int i = 0; i < 32; ++i) {
                a0 = fmaf(w0[i], x[i], a0);
                a1 = fmaf(w1[i], x[i], a1);
            }
            lo.h[t] = (__fp16)fmaxf(a0, 0.0f);
            hi.h[t] = (__fp16)fmaxf(a1, 0.0f);
        }
        h_lo = lo.v; h_hi = hi.v;
    }

    // ---- Phase B: tmp2 quarter (mp = quad*4..+4), pairs (m', m'+16) ----
    half2_t t2[4][3];
    {
        float bas[18];
        const float2* bv = (const float2*)(basis + (size_t)e * 18);
        #pragma unroll
        for (int i = 0; i < 9; ++i) { float2 t = bv[i]; bas[2*i] = t.x; bas[2*i+1] = t.y; }
        const float* fp = f + (size_t)src[e] * 48 + quad*6;
        float fl[6], fh[6];
        #pragma unroll
        for (int i = 0; i < 3; ++i) {
            float2 a = *(const float2*)(fp + 2*i);      fl[2*i] = a.x; fl[2*i+1] = a.y;
            float2 b = *(const float2*)(fp + 24 + 2*i); fh[2*i] = b.x; fh[2*i+1] = b.y;
        }
        #pragma unroll
        for (int jj = 0; jj < 4; ++jj) {
            const int mr = (jj >> 1) * 3;
            const int rb = (jj & 1) * 3;
            #pragma unroll
            for (int d = 0; d < 3; ++d) {
                float lo = fmaf(fl[mr+0], bas[rb+d],
                           fmaf(fl[mr+1], bas[6+rb+d], fl[mr+2] * bas[12+rb+d]));
                float hi = fmaf(fh[mr+0], bas[rb+d],
                           fmaf(fh[mr+1], bas[6+rb+d], fh[mr+2] * bas[12+rb+d]));
                t2[jj][d] = pk(lo, hi);
            }
        }
    }

    // ---- pass 1: k rows (c = 0..7) ----
    float kreg[8][3];
    CONV_GROUP(0, { kreg[cg][0]=p0; kreg[cg][1]=p1; kreg[cg][2]=p2; });

    // ---- pass 2: q rows (c = 8..15) -> scores ----
    __syncthreads();
    STAGE_W2(1);
    __syncthreads();
    float sreg[4];
    CONV_GROUP(8, {
        float s_ = p0*kreg[cg][0] + p1*kreg[cg][1] + p2*kreg[cg][2];
        if ((cg & 1) == 0) sreg[cg>>1] = s_; else sreg[cg>>1] += s_;
    });

    #pragma unroll
    for (int hh = 0; hh < 4; ++hh) {
        float s = sreg[hh] * TEMP;
        sreg[hh] = (s > 0.0f) ? s : 0.2f * s;
    }
    if (quad == 3) {
        *(float4*)(sc_out + (size_t)e*4) = make_float4(sreg[0], sreg[1], sreg[2], sreg[3]);
    }

    // ---- pass 3: v rows (c = 16..23) ----
    __syncthreads();
    STAGE_W2(2);
    __syncthreads();
    float vreg[8][3];
    CONV_GROUP(16, { vreg[cg][0]=p0; vreg[cg][1]=p1; vreg[cg][2]=p2; });

    float* vb = v_out + (size_t)e * 24;
    if (quad == 0) {
        *(float4*)(vb+0) = make_float4(vreg[0][0], vreg[0][1], vreg[0][2], vreg[1][0]);
        *(float4*)(vb+4) = make_float4(vreg[1][1], vreg[1][2], vreg[2][0], vreg[2][1]);
    } else if (quad == 1) {
        *(float4*)(vb+8)  = make_float4(vreg[2][2], vreg[3][0], vreg[3][1], vreg[3][2]);
        *(float4*)(vb+12) = make_float4(vreg[4][0], vreg[4][1], vreg[4][2], vreg[5][0]);
    } else if (quad == 2) {
        *(float4*)(vb+16) = make_float4(vreg[5][1], vreg[5][2], vreg[6][0], vreg[6][1]);
        *(float4*)(vb+20) = make_float4(vreg[6][2], vreg[7][0], vreg[7][1], vreg[7][2]);
    }
}

// ---- gather: one wave per node; static buckets (idx[n*SLOTS + i], i < cnt[n]) ----
__global__ __launch_bounds__(256)
void gather_kernel(const int* __restrict__ cnt, const int* __restrict__ idx,
                   const float* __restrict__ sc, const float* __restrict__ v,
                   float* __restrict__ out)
{
    const int lane = threadIdx.x & 63;
    const int wid  = threadIdx.x >> 6;
    const int n = blockIdx.x * 4 + wid;
    if (n >= N_NODES) return;
    int deg = cnt[n];
    if (deg > SLOTS) deg = SLOTS;
    const int* __restrict__ nb = idx + n * SLOTS;

    // phase 1: per-head max
    const int i2 = lane >> 2, h = lane & 3;
    float m = -1e30f;
    for (int i = i2; i < deg; i += 16) {
        m = fmaxf(m, sc[nb[i]*4 + h]);
    }
    m = fmaxf(m, __shfl_xor(m, 4));
    m = fmaxf(m, __shfl_xor(m, 8));
    m = fmaxf(m, __shfl_xor(m, 16));
    m = fmaxf(m, __shfl_xor(m, 32));

    // phase 2: lanes j and j+32 (j<24) split the edge range
    const int j = lane & 31;
    const int half = lane >> 5;
    const int hd = (j < 24) ? (j / 6) : 0;
    float mh = __shfl(m, hd);

    float acc = 0.f, den = 0.f;
    if (j < 24) {
        for (int i = half; i < deg; i += 2) {
            int eid = nb[i];
            float ex = __expf(sc[eid*4 + hd] - mh);
            den += ex;
            acc = fmaf(ex, v[eid*24 + j], acc);
        }
    }
    acc += __shfl_xor(acc, 32);
    den += __shfl_xor(den, 32);
    if (half == 0 && j < 24) {
        out[n*24 + j] = (den > 0.f) ? (acc / den) : 0.f;
    }
}

extern "C" void kernel_launch(void* const* d_in, const int* in_sizes, int n_in,
                              void* d_out, int out_size, void* d_ws, size_t ws_size,
                              hipStream_t stream)
{
    const int*   src   = (const int*)d_in[0];
    const int*   dst   = (const int*)d_in[1];
    const float* basis = (const float*)d_in[2];
    const float* ef    = (const float*)d_in[3];
    const float* f     = (const float*)d_in[4];
    const float* W1    = (const float*)d_in[5];
    const float* b1    = (const float*)d_in[6];
    const float* W2    = (const float*)d_in[7];
    const float* b2    = (const float*)d_in[8];
    float* out = (float*)d_out;

    float*    v_buf  = (float*)d_ws;                              // E*24 f32 (15.36 MB)
    float*    sc_buf = v_buf + (size_t)E_EDGES * 24;              // E*4 f32  (2.56 MB)
    unsigned* w2p    = (unsigned*)(sc_buf + (size_t)E_EDGES * 4); // 24576 u32 (96 KB)
    int*      cnt    = (int*)(w2p + 24576);                       // N (40 KB)
    int*      idx    = cnt + N_NODES;                             // N*SLOTS (2.56 MB)

    prep_kernel<<<96, 256, 0, stream>>>(W2, w2p, cnt);

    fused_kernel<<<E_EDGES / 64, 256, 0, stream>>>(src, dst, basis, ef, f,
                                                   W1, b1, (const uint4*)w2p, b2,
                                                   v_buf, sc_buf, cnt, idx);

    gather_kernel<<<(N_NODES + 3) / 4, 256, 0, stream>>>(cnt, idx, sc_buf, v_buf, out);
}